// Round 1
// baseline (772.507 us; speedup 1.0000x reference)
//
#include <hip/hip_runtime.h>
#include <math.h>

// Problem constants (from reference)
constexpr int BS = 16384;
constexpr int NC = 8192;
constexpr int THREADS = 256;
constexpr int V4PT = NC / (THREADS * 4);   // 8 float4 per thread (32 floats)

__global__ void zero_out_kernel(float* out) { out[0] = 0.0f; }

__launch_bounds__(THREADS)
__global__ void self_filter_loss_kernel(const float* __restrict__ x,
                                        const int* __restrict__ tgt,
                                        float* __restrict__ out) {
    const int row  = blockIdx.x;
    const int t    = threadIdx.x;
    const int wave = t >> 6;
    const int lane = t & 63;

    const float4* rowp = reinterpret_cast<const float4*>(x + (size_t)row * NC);
    const int tr = tgt[row];

    __shared__ float s_xt;
    __shared__ float s_m[4];
    __shared__ float s_se[4], s_xl[4], s_l[4];

    // ---- Load entire row into registers (single HBM pass), capture x[target]
    float4 v[V4PT];
#pragma unroll
    for (int i = 0; i < V4PT; ++i) {
        const int idx4 = i * THREADS + t;       // coalesced float4 index
        v[i] = rowp[idx4];
        const int base = idx4 * 4;
        const int d = tr - base;
        if (d >= 0 && d < 4) {
            const int k = tr & 3;
            const float val = (k == 0) ? v[i].x : (k == 1) ? v[i].y
                             : (k == 2) ? v[i].z : v[i].w;
            s_xt = val;                          // exactly one thread matches
        }
    }

    // ---- Block max reduction
    float m = -INFINITY;
#pragma unroll
    for (int i = 0; i < V4PT; ++i)
        m = fmaxf(m, fmaxf(fmaxf(v[i].x, v[i].y), fmaxf(v[i].z, v[i].w)));
#pragma unroll
    for (int off = 32; off > 0; off >>= 1)
        m = fmaxf(m, __shfl_xor(m, off, 64));
    if (lane == 0) s_m[wave] = m;
    __syncthreads();                             // covers s_m and s_xt
    m = fmaxf(fmaxf(s_m[0], s_m[1]), fmaxf(s_m[2], s_m[3]));
    const float xt = s_xt;
    const float K  = __expf(m - xt);             // exp(x-xt) = exp(x-m)*K

    // ---- Single fused pass over registers: sum_exp, sum x*lat, sum lat
    float sum_e = 0.0f, sum_xl = 0.0f, sum_l = 0.0f;
#pragma unroll
    for (int i = 0; i < V4PT; ++i) {
        const float xs[4] = { v[i].x, v[i].y, v[i].z, v[i].w };
#pragma unroll
        for (int k = 0; k < 4; ++k) {
            const float xv  = xs[k];
            const float ex  = __expf(xv - m);    // exp(x - m)
            sum_e += ex;
            const float conf = 0.2f - ex * K;    // 0.2 - p_j/p_t
            const float lat  = conf > 0.0f ? conf : 0.0f;
            sum_xl = fmaf(xv, lat, sum_xl);
            sum_l += lat;
        }
    }

    // ---- Block reduce the three sums
#pragma unroll
    for (int off = 32; off > 0; off >>= 1) {
        sum_e  += __shfl_xor(sum_e,  off, 64);
        sum_xl += __shfl_xor(sum_xl, off, 64);
        sum_l  += __shfl_xor(sum_l,  off, 64);
    }
    if (lane == 0) { s_se[wave] = sum_e; s_xl[wave] = sum_xl; s_l[wave] = sum_l; }
    __syncthreads();

    if (t == 0) {
        const float S   = s_se[0] + s_se[1] + s_se[2] + s_se[3];
        const float XL  = s_xl[0] + s_xl[1] + s_xl[2] + s_xl[3];
        const float L   = s_l[0]  + s_l[1]  + s_l[2]  + s_l[3];
        const float lse = __logf(S);
        const float off_ = m + lse;              // log_prob_j = x_j - off_
        const float total = XL - off_ * L;       // sum_j log_prob_j * latent_j
        const float lp_t  = xt - off_;
        const float s_row = -lp_t - (0.1f / (float)(NC - 1)) * total;
        atomicAdd(out, s_row * (1.0f / (float)BS));
    }
}

extern "C" void kernel_launch(void* const* d_in, const int* in_sizes, int n_in,
                              void* d_out, int out_size, void* d_ws, size_t ws_size,
                              hipStream_t stream) {
    const float* x   = (const float*)d_in[0];
    const int*   tgt = (const int*)d_in[1];
    float*       out = (float*)d_out;

    // d_out is poisoned (0xAA) before timed launches — zero it on-stream.
    zero_out_kernel<<<1, 1, 0, stream>>>(out);
    self_filter_loss_kernel<<<BS, THREADS, 0, stream>>>(x, tgt, out);
}

// Round 3
// 638.692 us; speedup vs baseline: 1.2095x; 1.2095x over previous
//
#include <hip/hip_runtime.h>
#include <math.h>

// Problem constants (from reference)
constexpr int BS = 16384;
constexpr int NC = 8192;
constexpr int THREADS = 256;
constexpr int V4PT = NC / (THREADS * 4);   // 8 float4 per thread (32 floats)

using nt4 = __attribute__((ext_vector_type(4))) float;   // nontemporal-loadable

// ---------------------------------------------------------------------------
// Pass 1: one block per row. Row is read from HBM exactly once into registers
// (8x float4/thread, nontemporal — no reuse, don't pollute L2). Produces the
// per-row loss contribution into d_ws (deterministic, no atomics).
// ---------------------------------------------------------------------------
__launch_bounds__(THREADS)
__global__ void self_filter_row_kernel(const float* __restrict__ x,
                                       const int* __restrict__ tgt,
                                       float* __restrict__ partial) {
    const int row  = blockIdx.x;
    const int t    = threadIdx.x;
    const int wave = t >> 6;
    const int lane = t & 63;

    const nt4* rowp = reinterpret_cast<const nt4*>(x + (size_t)row * NC);
    const int tr = tgt[row];

    __shared__ float s_xt;
    __shared__ float s_m[4];
    __shared__ float s_se[4], s_xl[4], s_l[4];

    // ---- Load entire row into registers (single HBM pass), capture x[target]
    nt4 v[V4PT];
#pragma unroll
    for (int i = 0; i < V4PT; ++i) {
        const int idx4 = i * THREADS + t;       // coalesced float4 index
        v[i] = __builtin_nontemporal_load(&rowp[idx4]);
        const int base = idx4 * 4;
        const int d = tr - base;
        if (d >= 0 && d < 4) {
            s_xt = v[i][tr & 3];                 // exactly one thread matches
        }
    }

    // ---- Block max reduction (numerical safety; cheap)
    float m = -INFINITY;
#pragma unroll
    for (int i = 0; i < V4PT; ++i)
        m = fmaxf(m, fmaxf(fmaxf(v[i][0], v[i][1]), fmaxf(v[i][2], v[i][3])));
#pragma unroll
    for (int off = 32; off > 0; off >>= 1)
        m = fmaxf(m, __shfl_xor(m, off, 64));
    if (lane == 0) s_m[wave] = m;
    __syncthreads();                             // covers s_m and s_xt
    m = fmaxf(fmaxf(s_m[0], s_m[1]), fmaxf(s_m[2], s_m[3]));
    const float xt = s_xt;
    const float K  = __expf(m - xt);             // exp(x-xt) = exp(x-m)*K

    // ---- Single fused pass over registers: sum_exp, sum x*lat, sum lat
    float sum_e = 0.0f, sum_xl = 0.0f, sum_l = 0.0f;
#pragma unroll
    for (int i = 0; i < V4PT; ++i) {
#pragma unroll
        for (int k = 0; k < 4; ++k) {
            const float xv  = v[i][k];
            const float ex  = __expf(xv - m);    // exp(x - m)
            sum_e += ex;
            const float conf = 0.2f - ex * K;    // 0.2 - p_j/p_t
            const float lat  = conf > 0.0f ? conf : 0.0f;
            sum_xl = fmaf(xv, lat, sum_xl);
            sum_l += lat;
        }
    }

    // ---- Block reduce the three sums
#pragma unroll
    for (int off = 32; off > 0; off >>= 1) {
        sum_e  += __shfl_xor(sum_e,  off, 64);
        sum_xl += __shfl_xor(sum_xl, off, 64);
        sum_l  += __shfl_xor(sum_l,  off, 64);
    }
    if (lane == 0) { s_se[wave] = sum_e; s_xl[wave] = sum_xl; s_l[wave] = sum_l; }
    __syncthreads();

    if (t == 0) {
        const float S   = s_se[0] + s_se[1] + s_se[2] + s_se[3];
        const float XL  = s_xl[0] + s_xl[1] + s_xl[2] + s_xl[3];
        const float L   = s_l[0]  + s_l[1]  + s_l[2]  + s_l[3];
        const float lse = __logf(S);
        const float off_ = m + lse;              // log_prob_j = x_j - off_
        const float total = XL - off_ * L;       // sum_j log_prob_j * latent_j
        const float lp_t  = xt - off_;
        partial[row] = -lp_t - (0.1f / (float)(NC - 1)) * total;
    }
}

// ---------------------------------------------------------------------------
// Pass 2: one block sums the 16384 per-row partials and writes the scalar.
// Writes d_out directly (harness poisons it to 0xAA — we fully overwrite).
// ---------------------------------------------------------------------------
__launch_bounds__(THREADS)
__global__ void self_filter_reduce_kernel(const float* __restrict__ partial,
                                          float* __restrict__ out) {
    const int t    = threadIdx.x;
    const int wave = t >> 6;
    const int lane = t & 63;
    __shared__ float s_s[4];

    const nt4* p4 = reinterpret_cast<const nt4*>(partial);
    float s = 0.0f;
#pragma unroll
    for (int i = 0; i < BS / (THREADS * 4); ++i) {   // 16 float4 per thread
        const nt4 v = p4[i * THREADS + t];
        s += (v[0] + v[1]) + (v[2] + v[3]);
    }
#pragma unroll
    for (int off = 32; off > 0; off >>= 1)
        s += __shfl_xor(s, off, 64);
    if (lane == 0) s_s[wave] = s;
    __syncthreads();
    if (t == 0)
        out[0] = (s_s[0] + s_s[1] + s_s[2] + s_s[3]) * (1.0f / (float)BS);
}

extern "C" void kernel_launch(void* const* d_in, const int* in_sizes, int n_in,
                              void* d_out, int out_size, void* d_ws, size_t ws_size,
                              hipStream_t stream) {
    const float* x   = (const float*)d_in[0];
    const int*   tgt = (const int*)d_in[1];
    float*       out = (float*)d_out;
    float*       partial = (float*)d_ws;          // 64 KiB of scratch

    self_filter_row_kernel<<<BS, THREADS, 0, stream>>>(x, tgt, partial);
    self_filter_reduce_kernel<<<1, THREADS, 0, stream>>>(partial, out);
}